// Round 2
// baseline (403.767 us; speedup 1.0000x reference)
//
#include <hip/hip_runtime.h>

#define B_N 4096
#define M_N 16384
#define D_N 512
#define NC_N 100
#define NCP 112

typedef float f32x4 __attribute__((ext_vector_type(4)));
typedef short bf16x8 __attribute__((ext_vector_type(8)));

__device__ __forceinline__ unsigned short f2bf(float f) {
  unsigned int u = __float_as_uint(f);
  u += 0x7FFFu + ((u >> 16) & 1u);
  return (unsigned short)(u >> 16);
}

// Convert rows of src (nrows x 512 fp32) to bf16 and compute squared norms.
__global__ void prep_rows(const float* __restrict__ src, unsigned short* __restrict__ dst,
                          float* __restrict__ norms) {
  int row = blockIdx.x * 4 + (threadIdx.x >> 6);
  int lane = threadIdx.x & 63;
  const float4* s = (const float4*)(src + (size_t)row * D_N);
  float4 v0 = s[lane * 2];
  float4 v1 = s[lane * 2 + 1];
  float acc = v0.x * v0.x + v0.y * v0.y + v0.z * v0.z + v0.w * v0.w +
              v1.x * v1.x + v1.y * v1.y + v1.z * v1.z + v1.w * v1.w;
  unsigned int p0 = f2bf(v0.x) | ((unsigned int)f2bf(v0.y) << 16);
  unsigned int p1 = f2bf(v0.z) | ((unsigned int)f2bf(v0.w) << 16);
  unsigned int p2 = f2bf(v1.x) | ((unsigned int)f2bf(v1.y) << 16);
  unsigned int p3 = f2bf(v1.z) | ((unsigned int)f2bf(v1.w) << 16);
  uint4 w4; w4.x = p0; w4.y = p1; w4.z = p2; w4.w = p3;
  *(uint4*)(dst + (size_t)row * D_N + lane * 8) = w4;
  #pragma unroll
  for (int off = 1; off < 64; off <<= 1) acc += __shfl_xor(acc, off);
  if (lane == 0) norms[row] = acc;
}

// C (M x 100 fp32) -> CT (112 x M bf16), rows 100..111 zero.
__global__ void prep_ct(const float* __restrict__ C, unsigned short* __restrict__ CT) {
  int m = blockIdx.x * 256 + threadIdx.x;
  int c = blockIdx.y;
  unsigned short v = 0;
  if (c < NC_N) v = f2bf(C[(size_t)m * NC_N + c]);
  CT[(size_t)c * M_N + m] = v;
}

// Main fused kernel: scores = -sqrt(aa+xx-2*A.X)/4 ; p = exp(score) (no max
// subtraction needed: score in [-10,0]); accumulate out^T += C^T * P and den.
__global__ __launch_bounds__(512, 2)
void fused_main(const unsigned short* __restrict__ Abf,
                const unsigned short* __restrict__ Xbf,
                const unsigned short* __restrict__ CTbf,
                const float* __restrict__ aa, const float* __restrict__ xx,
                float* __restrict__ pacc, float* __restrict__ pden, int splitm) {
  __shared__ unsigned short Xl[64 * 520];        // X tile, padded stride (16B aligned rows)
  __shared__ unsigned short Pl[8][64 * 40];      // per-wave P^T tile [b][m], stride 40
  __shared__ float Cacc[NCP * 64];
  __shared__ float Cden[64];

  const int t = threadIdx.x;
  const int w = t >> 6;
  const int l = t & 63;
  const int g = l >> 4;
  const int r16 = l & 15;
  const int bbase = blockIdx.x * 64;
  const int sidx = blockIdx.y;

  // stage X tile (64 x 512 bf16) into LDS
  #pragma unroll
  for (int i = 0; i < 8; ++i) {
    int q = t + 512 * i;
    int row = q >> 6, col8 = q & 63;
    uint4 v = *(const uint4*)(Xbf + (size_t)(bbase + row) * D_N + col8 * 8);
    *(uint4*)(&Xl[row * 520 + col8 * 8]) = v;
  }
  __syncthreads();

  float xxv[4];
  #pragma unroll
  for (int bs = 0; bs < 4; ++bs) xxv[bs] = xx[bbase + bs * 16 + r16];

  f32x4 oacc[7][4];
  #pragma unroll
  for (int ct = 0; ct < 7; ++ct)
    #pragma unroll
    for (int bs = 0; bs < 4; ++bs) oacc[ct][bs] = (f32x4){0.f, 0.f, 0.f, 0.f};
  float den[4] = {0.f, 0.f, 0.f, 0.f};

  unsigned short* Plw = &Pl[w][0];

  for (int T = sidx + splitm * w; T < M_N / 32; T += splitm * 8) {
    int m0 = T * 32;
    f32x4 sacc[2][4];
    #pragma unroll
    for (int ms = 0; ms < 2; ++ms)
      #pragma unroll
      for (int bs = 0; bs < 4; ++bs) sacc[ms][bs] = (f32x4){0.f, 0.f, 0.f, 0.f};

    #pragma unroll 4
    for (int ki = 0; ki < 16; ++ki) {
      int k0 = ki * 32 + 8 * g;
      bf16x8 a0 = *(const bf16x8*)(Abf + (size_t)(m0 + r16) * D_N + k0);
      bf16x8 a1 = *(const bf16x8*)(Abf + (size_t)(m0 + 16 + r16) * D_N + k0);
      #pragma unroll
      for (int bs = 0; bs < 4; ++bs) {
        bf16x8 xf = *(const bf16x8*)(&Xl[(bs * 16 + r16) * 520 + k0]);
        sacc[0][bs] = __builtin_amdgcn_mfma_f32_16x16x32_bf16(a0, xf, sacc[0][bs], 0, 0, 0);
        sacc[1][bs] = __builtin_amdgcn_mfma_f32_16x16x32_bf16(a1, xf, sacc[1][bs], 0, 0, 0);
      }
    }

    // epilogue: d2 -> dist -> p = exp(-dist/4), write P^T tile to per-wave LDS
    #pragma unroll
    for (int ms = 0; ms < 2; ++ms) {
      f32x4 aa4 = *(const f32x4*)(aa + m0 + ms * 16 + 4 * g);
      #pragma unroll
      for (int bs = 0; bs < 4; ++bs) {
        f32x4 s4 = sacc[ms][bs];
        float e[4];
        #pragma unroll
        for (int r = 0; r < 4; ++r) {
          float d2 = aa4[r] + xxv[bs] - 2.0f * s4[r];
          float dist = sqrtf(fmaxf(d2, 0.0f));
          e[r] = exp2f(-0.36067376022224085f * dist);  // exp(-dist/4)
        }
        den[bs] += (e[0] + e[1]) + (e[2] + e[3]);
        uint2 pk;
        pk.x = f2bf(e[0]) | ((unsigned int)f2bf(e[1]) << 16);
        pk.y = f2bf(e[2]) | ((unsigned int)f2bf(e[3]) << 16);
        *(uint2*)(&Plw[(bs * 16 + r16) * 40 + ms * 16 + 4 * g]) = pk;
      }
    }

    // out^T += C^T * P  (K = 32 = this m-tile)
    bf16x8 pf[4];
    #pragma unroll
    for (int bs = 0; bs < 4; ++bs)
      pf[bs] = *(const bf16x8*)(&Plw[(bs * 16 + r16) * 40 + 8 * g]);
    #pragma unroll
    for (int ct = 0; ct < 7; ++ct) {
      bf16x8 cf = *(const bf16x8*)(CTbf + (size_t)(ct * 16 + r16) * M_N + m0 + 8 * g);
      #pragma unroll
      for (int bs = 0; bs < 4; ++bs)
        oacc[ct][bs] = __builtin_amdgcn_mfma_f32_16x16x32_bf16(cf, pf[bs], oacc[ct][bs], 0, 0, 0);
    }
  }

  // reduce den across the 4 lane-groups (column sums)
  #pragma unroll
  for (int bs = 0; bs < 4; ++bs) {
    float d = den[bs];
    d += __shfl_xor(d, 16);
    d += __shfl_xor(d, 32);
    den[bs] = d;
  }

  // combine the 8 waves' partials in LDS
  __syncthreads();
  for (int i = t; i < NCP * 64; i += 512) Cacc[i] = 0.f;
  if (t < 64) Cden[t] = 0.f;
  __syncthreads();

  for (int ww = 0; ww < 8; ++ww) {
    if (w == ww) {
      #pragma unroll
      for (int ct = 0; ct < 7; ++ct)
        #pragma unroll
        for (int bs = 0; bs < 4; ++bs)
          #pragma unroll
          for (int r = 0; r < 4; ++r)
            Cacc[(ct * 16 + 4 * g + r) * 64 + bs * 16 + r16] += oacc[ct][bs][r];
      if (g == 0)
        #pragma unroll
        for (int bs = 0; bs < 4; ++bs) Cden[bs * 16 + r16] += den[bs];
    }
    __syncthreads();
  }

  // write partial accumulators: pacc[s][c][b], pden[s][b]
  float* paccS = pacc + (size_t)sidx * NCP * B_N;
  for (int i = t; i < NCP * 64; i += 512) {
    int c = i >> 6, bl = i & 63;
    paccS[(size_t)c * B_N + bbase + bl] = Cacc[i];
  }
  if (t < 64) pden[sidx * B_N + bbase + t] = Cden[t];
}

__global__ void finalize(const float* __restrict__ pacc, const float* __restrict__ pden,
                         float* __restrict__ out, int splitm) {
  int b = blockIdx.x * 256 + threadIdx.x;
  float dn = 0.f;
  for (int s = 0; s < splitm; ++s) dn += pden[s * B_N + b];
  float inv = 1.0f / dn;
  for (int c = 0; c < NC_N; ++c) {
    float a = 0.f;
    for (int s = 0; s < splitm; ++s) a += pacc[((size_t)s * NCP + c) * B_N + b];
    out[b * NC_N + c] = a * inv;
  }
}

extern "C" void kernel_launch(void* const* d_in, const int* in_sizes, int n_in,
                              void* d_out, int out_size, void* d_ws, size_t ws_size,
                              hipStream_t stream) {
  const float* X = (const float*)d_in[0];
  const float* A = (const float*)d_in[1];
  const float* C = (const float*)d_in[2];
  float* out = (float*)d_out;

  char* ws = (char*)d_ws;
  size_t off = 0;
  auto alloc = [&](size_t bytes) -> void* {
    void* p = ws + off;
    off += (bytes + 255) & ~(size_t)255;
    return p;
  };
  unsigned short* Abf = (unsigned short*)alloc((size_t)M_N * D_N * 2);
  unsigned short* Xbf = (unsigned short*)alloc((size_t)B_N * D_N * 2);
  unsigned short* CT  = (unsigned short*)alloc((size_t)NCP * M_N * 2);
  float* aa = (float*)alloc((size_t)M_N * 4);
  float* xx = (float*)alloc((size_t)B_N * 4);

  size_t per_split = ((size_t)NCP * B_N * 4 + 256) + ((size_t)B_N * 4 + 256);
  int splitm = 8;
  while (splitm > 1 && off + (size_t)splitm * per_split > ws_size) splitm >>= 1;
  float* pacc = (float*)alloc((size_t)splitm * NCP * B_N * 4);
  float* pden = (float*)alloc((size_t)splitm * B_N * 4);

  prep_rows<<<M_N / 4, 256, 0, stream>>>(A, Abf, aa);
  prep_rows<<<B_N / 4, 256, 0, stream>>>(X, Xbf, xx);
  prep_ct<<<dim3(M_N / 256, NCP), 256, 0, stream>>>(C, CT);
  fused_main<<<dim3(B_N / 64, splitm), 512, 0, stream>>>(Abf, Xbf, CT, aa, xx, pacc, pden, splitm);
  finalize<<<B_N / 256, 256, 0, stream>>>(pacc, pden, out, splitm);
}

// Round 3
// 221.128 us; speedup vs baseline: 1.8259x; 1.8259x over previous
//
#include <hip/hip_runtime.h>

#define B_N 4096
#define M_N 16384
#define D_N 512
#define NC_N 100
#define NCP 112

typedef float f32x4 __attribute__((ext_vector_type(4)));
typedef short bf16x8 __attribute__((ext_vector_type(8)));

__device__ __forceinline__ unsigned short f2bf(float f) {
  unsigned int u = __float_as_uint(f);
  u += 0x7FFFu + ((u >> 16) & 1u);
  return (unsigned short)(u >> 16);
}

// Convert rows of src (nrows x 512 fp32) to bf16 and compute squared norms.
__global__ void prep_rows(const float* __restrict__ src, unsigned short* __restrict__ dst,
                          float* __restrict__ norms) {
  int row = blockIdx.x * 4 + (threadIdx.x >> 6);
  int lane = threadIdx.x & 63;
  const float4* s = (const float4*)(src + (size_t)row * D_N);
  float4 v0 = s[lane * 2];
  float4 v1 = s[lane * 2 + 1];
  float acc = v0.x * v0.x + v0.y * v0.y + v0.z * v0.z + v0.w * v0.w +
              v1.x * v1.x + v1.y * v1.y + v1.z * v1.z + v1.w * v1.w;
  unsigned int p0 = f2bf(v0.x) | ((unsigned int)f2bf(v0.y) << 16);
  unsigned int p1 = f2bf(v0.z) | ((unsigned int)f2bf(v0.w) << 16);
  unsigned int p2 = f2bf(v1.x) | ((unsigned int)f2bf(v1.y) << 16);
  unsigned int p3 = f2bf(v1.z) | ((unsigned int)f2bf(v1.w) << 16);
  uint4 w4; w4.x = p0; w4.y = p1; w4.z = p2; w4.w = p3;
  *(uint4*)(dst + (size_t)row * D_N + lane * 8) = w4;
  #pragma unroll
  for (int off = 1; off < 64; off <<= 1) acc += __shfl_xor(acc, off);
  if (lane == 0) norms[row] = acc;
}

// C (M x 100 fp32) -> CT (112 x M bf16), rows 100..111 zero.
__global__ void prep_ct(const float* __restrict__ C, unsigned short* __restrict__ CT) {
  int m = blockIdx.x * 256 + threadIdx.x;
  int c = blockIdx.y;
  unsigned short v = 0;
  if (c < NC_N) v = f2bf(C[(size_t)m * NC_N + c]);
  CT[(size_t)c * M_N + m] = v;
}

// Main fused kernel: scores = -sqrt(aa+xx-2*A.X)/4 ; p = exp(score) (no max
// subtraction needed: score in [-10,0]); accumulate out^T += C^T * P and den.
__global__ __launch_bounds__(512, 2)
void fused_main(const unsigned short* __restrict__ Abf,
                const unsigned short* __restrict__ Xbf,
                const unsigned short* __restrict__ CTbf,
                const float* __restrict__ aa, const float* __restrict__ xx,
                float* __restrict__ pacc, float* __restrict__ pden, int splitm) {
  __shared__ unsigned short Xl[64 * 520];        // X tile, padded stride (16B aligned rows)
  __shared__ unsigned short Pl[8][64 * 40];      // per-wave P^T tile [b][m], stride 40
  __shared__ float Cacc[NCP * 64];
  __shared__ float Cden[64];

  const int t = threadIdx.x;
  const int w = t >> 6;
  const int l = t & 63;
  const int g = l >> 4;
  const int r16 = l & 15;
  const int bbase = blockIdx.x * 64;
  const int sidx = blockIdx.y;

  // stage X tile (64 x 512 bf16) into LDS
  #pragma unroll
  for (int i = 0; i < 8; ++i) {
    int q = t + 512 * i;
    int row = q >> 6, col8 = q & 63;
    uint4 v = *(const uint4*)(Xbf + (size_t)(bbase + row) * D_N + col8 * 8);
    *(uint4*)(&Xl[row * 520 + col8 * 8]) = v;
  }
  __syncthreads();

  float xxv[4];
  #pragma unroll
  for (int bs = 0; bs < 4; ++bs) xxv[bs] = xx[bbase + bs * 16 + r16];

  f32x4 oacc[7][4];
  #pragma unroll
  for (int ct = 0; ct < 7; ++ct)
    #pragma unroll
    for (int bs = 0; bs < 4; ++bs) oacc[ct][bs] = (f32x4){0.f, 0.f, 0.f, 0.f};
  float den[4] = {0.f, 0.f, 0.f, 0.f};

  unsigned short* Plw = &Pl[w][0];

  for (int T = sidx + splitm * w; T < M_N / 32; T += splitm * 8) {
    int m0 = T * 32;
    f32x4 sacc[2][4];
    #pragma unroll
    for (int ms = 0; ms < 2; ++ms)
      #pragma unroll
      for (int bs = 0; bs < 4; ++bs) sacc[ms][bs] = (f32x4){0.f, 0.f, 0.f, 0.f};

    #pragma unroll 4
    for (int ki = 0; ki < 16; ++ki) {
      int k0 = ki * 32 + 8 * g;
      bf16x8 a0 = *(const bf16x8*)(Abf + (size_t)(m0 + r16) * D_N + k0);
      bf16x8 a1 = *(const bf16x8*)(Abf + (size_t)(m0 + 16 + r16) * D_N + k0);
      #pragma unroll
      for (int bs = 0; bs < 4; ++bs) {
        bf16x8 xf = *(const bf16x8*)(&Xl[(bs * 16 + r16) * 520 + k0]);
        sacc[0][bs] = __builtin_amdgcn_mfma_f32_16x16x32_bf16(a0, xf, sacc[0][bs], 0, 0, 0);
        sacc[1][bs] = __builtin_amdgcn_mfma_f32_16x16x32_bf16(a1, xf, sacc[1][bs], 0, 0, 0);
      }
    }

    // epilogue: d2 -> dist -> p = exp(-dist/4), write P^T tile to per-wave LDS
    #pragma unroll
    for (int ms = 0; ms < 2; ++ms) {
      f32x4 aa4 = *(const f32x4*)(aa + m0 + ms * 16 + 4 * g);
      #pragma unroll
      for (int bs = 0; bs < 4; ++bs) {
        f32x4 s4 = sacc[ms][bs];
        float e[4];
        #pragma unroll
        for (int r = 0; r < 4; ++r) {
          float d2 = aa4[r] + xxv[bs] - 2.0f * s4[r];
          float dist = sqrtf(fmaxf(d2, 0.0f));
          e[r] = exp2f(-0.36067376022224085f * dist);  // exp(-dist/4)
        }
        den[bs] += (e[0] + e[1]) + (e[2] + e[3]);
        uint2 pk;
        pk.x = f2bf(e[0]) | ((unsigned int)f2bf(e[1]) << 16);
        pk.y = f2bf(e[2]) | ((unsigned int)f2bf(e[3]) << 16);
        *(uint2*)(&Plw[(bs * 16 + r16) * 40 + ms * 16 + 4 * g]) = pk;
      }
    }

    // out^T += C^T * P  (K = 32 = this m-tile)
    bf16x8 pf[4];
    #pragma unroll
    for (int bs = 0; bs < 4; ++bs)
      pf[bs] = *(const bf16x8*)(&Plw[(bs * 16 + r16) * 40 + 8 * g]);
    #pragma unroll
    for (int ct = 0; ct < 7; ++ct) {
      bf16x8 cf = *(const bf16x8*)(CTbf + (size_t)(ct * 16 + r16) * M_N + m0 + 8 * g);
      #pragma unroll
      for (int bs = 0; bs < 4; ++bs)
        oacc[ct][bs] = __builtin_amdgcn_mfma_f32_16x16x32_bf16(cf, pf[bs], oacc[ct][bs], 0, 0, 0);
    }
  }

  // reduce den across the 4 lane-groups (column sums)
  #pragma unroll
  for (int bs = 0; bs < 4; ++bs) {
    float d = den[bs];
    d += __shfl_xor(d, 16);
    d += __shfl_xor(d, 32);
    den[bs] = d;
  }

  // combine the 8 waves' partials in LDS
  __syncthreads();
  for (int i = t; i < NCP * 64; i += 512) Cacc[i] = 0.f;
  if (t < 64) Cden[t] = 0.f;
  __syncthreads();

  for (int ww = 0; ww < 8; ++ww) {
    if (w == ww) {
      #pragma unroll
      for (int ct = 0; ct < 7; ++ct)
        #pragma unroll
        for (int bs = 0; bs < 4; ++bs)
          #pragma unroll
          for (int r = 0; r < 4; ++r)
            Cacc[(ct * 16 + 4 * g + r) * 64 + bs * 16 + r16] += oacc[ct][bs][r];
      if (g == 0)
        #pragma unroll
        for (int bs = 0; bs < 4; ++bs) Cden[bs * 16 + r16] += den[bs];
    }
    __syncthreads();
  }

  // write partial accumulators: pacc[s][c][b], pden[s][b]
  float* paccS = pacc + (size_t)sidx * NCP * B_N;
  for (int i = t; i < NCP * 64; i += 512) {
    int c = i >> 6, bl = i & 63;
    paccS[(size_t)c * B_N + bbase + bl] = Cacc[i];
  }
  if (t < 64) pden[sidx * B_N + bbase + t] = Cden[t];
}

// Finalize: 256 blocks, each owns 16 b's; tile (16c x 16b) threads.
// Reads coalesced along b; LDS-staged transpose for coalesced out writes.
#define FB 16
__global__ __launch_bounds__(256)
void finalize(const float* __restrict__ pacc, const float* __restrict__ pden,
              float* __restrict__ out, int splitm) {
  __shared__ float tile[NC_N][FB];
  __shared__ float dinv[FB];
  const int t = threadIdx.x;
  const int b0 = blockIdx.x * FB;
  const int tb = t & 15;
  const int tc = t >> 4;

  if (t < FB) {
    float dn = 0.f;
    for (int s = 0; s < splitm; ++s) dn += pden[s * B_N + b0 + t];
    dinv[t] = 1.0f / dn;
  }

  for (int c = tc; c < NC_N; c += 16) {
    float a = 0.f;
    for (int s = 0; s < splitm; ++s)
      a += pacc[((size_t)s * NCP + c) * B_N + b0 + tb];
    tile[c][tb] = a;
  }
  __syncthreads();

  for (int i = t; i < FB * NC_N; i += 256) {
    int b = i / NC_N, c = i - b * NC_N;
    out[(size_t)(b0 + b) * NC_N + c] = tile[c][b] * dinv[b];
  }
}

extern "C" void kernel_launch(void* const* d_in, const int* in_sizes, int n_in,
                              void* d_out, int out_size, void* d_ws, size_t ws_size,
                              hipStream_t stream) {
  const float* X = (const float*)d_in[0];
  const float* A = (const float*)d_in[1];
  const float* C = (const float*)d_in[2];
  float* out = (float*)d_out;

  char* ws = (char*)d_ws;
  size_t off = 0;
  auto alloc = [&](size_t bytes) -> void* {
    void* p = ws + off;
    off += (bytes + 255) & ~(size_t)255;
    return p;
  };
  unsigned short* Abf = (unsigned short*)alloc((size_t)M_N * D_N * 2);
  unsigned short* Xbf = (unsigned short*)alloc((size_t)B_N * D_N * 2);
  unsigned short* CT  = (unsigned short*)alloc((size_t)NCP * M_N * 2);
  float* aa = (float*)alloc((size_t)M_N * 4);
  float* xx = (float*)alloc((size_t)B_N * 4);

  size_t per_split = ((size_t)NCP * B_N * 4 + 256) + ((size_t)B_N * 4 + 256);
  int splitm = 8;
  while (splitm > 1 && off + (size_t)splitm * per_split > ws_size) splitm >>= 1;
  float* pacc = (float*)alloc((size_t)splitm * NCP * B_N * 4);
  float* pden = (float*)alloc((size_t)splitm * B_N * 4);

  prep_rows<<<M_N / 4, 256, 0, stream>>>(A, Abf, aa);
  prep_rows<<<B_N / 4, 256, 0, stream>>>(X, Xbf, xx);
  prep_ct<<<dim3(M_N / 256, NCP), 256, 0, stream>>>(C, CT);
  fused_main<<<dim3(B_N / 64, splitm), 512, 0, stream>>>(Abf, Xbf, CT, aa, xx, pacc, pden, splitm);
  finalize<<<B_N / FB, 256, 0, stream>>>(pacc, pden, out, splitm);
}